// Round 10
// baseline (2482.382 us; speedup 1.0000x reference)
//
#include <hip/hip_runtime.h>
#include <float.h>

#define NB   8
#define NC   512
#define NT   4096
#define NCB  32
#define NK   1024
#define ND   32

// Eigen TensorContraction k-panel boundaries for K=512 on Zen4/5 (L1d=32KB,
// AVX-512 traits mr=48,nr=8): kc = ((32768-1536)/224) & ~7 = 136.
__constant__ int PB[5] = {0, 136, 272, 408, 512};

// ---- XLA:CPU (Eigen) bit-exact models ---------------------------------------
// dot: jnp.einsum('btd,kd->btk') -> Eigen contraction, K=32 (single panel):
// one ascending-k FMA chain from zero per output element.
__device__ __forceinline__ float dot_xla(const float* __restrict__ rf,
                                         const float* __restrict__ c) {
    float t = 0.f;
#pragma unroll
    for (int i = 0; i < ND; ++i) t = fmaf(rf[i], c[i], t);
    return t;
}

// cnorm: jnp.sum(cb*cb, -1) -> sequential ascending FMA chain (proven
// flip-irrelevant across R2..R8 variants).
__device__ __forceinline__ float cn_xla(const float* __restrict__ c) {
    float t = 0.f;
#pragma unroll
    for (int i = 0; i < ND; ++i) t = fmaf(c[i], c[i], t);
    return t;
}

// d = cn - 2*dot: x2 exact, one rounded subtract.
__device__ __forceinline__ float exact_d_ref(const float* __restrict__ rf,
                                             const float* __restrict__ c) {
    return __fsub_rn(cn_xla(c), __fmul_rn(2.0f, dot_xla(rf, c)));
}

__launch_bounds__(256, 2)
__global__ void rvq_kernel(const float* __restrict__ latent,
                           const float* __restrict__ projw,
                           const float* __restrict__ projb,
                           const float* __restrict__ cb,
                           float* __restrict__ out)
{
    __shared__ float wlds[ND * NC];     // 64 KB: w in phase B; cnf + mrg in phase C
    __shared__ float xbuf[64 * 36];     // projected x rows, padded stride 36

    const int tid  = threadIdx.x;
    const int lane = tid & 63;
    const int wv   = tid >> 6;
    const int b    = blockIdx.x >> 6;                 // 64 blocks per batch
    const int t    = ((blockIdx.x & 63) << 6) + lane; // token column

    // ---------- Phase A: stage proj_w [D][C] ----------
    for (int i = tid; i < ND * NC; i += 256) wlds[i] = projw[i];
    __syncthreads();

    // ---------- Phase B: projection — Eigen 4-panel kc=136 model ----------
    // x_d = (((chain[0,136) + chain[136,272)) + chain[272,408)) + chain[408,512))
    //       + bias; each chain = ascending-c FMA fold from zero; adds rounded.
    {
#pragma clang fp contract(off)
        const float* lat = latent + (size_t)b * NC * NT + t;
        const int d0 = wv * 8;                        // this wave's 8 dims
        float xv[8];
#pragma unroll
        for (int j = 0; j < 8; ++j) xv[j] = 0.f;

        for (int p = 0; p < 4; ++p) {
            float acc[8];
#pragma unroll
            for (int j = 0; j < 8; ++j) acc[j] = 0.f;
            const int c0 = PB[p], c1 = PB[p + 1];
            for (int c = c0; c < c1; ++c) {
                const float lv = lat[(size_t)c * NT];
#pragma unroll
                for (int j = 0; j < 8; ++j)
                    acc[j] = fmaf(wlds[(d0 + j) * NC + c], lv, acc[j]);
            }
            if (p == 0) {
#pragma unroll
                for (int j = 0; j < 8; ++j) xv[j] = acc[j];
            } else {
#pragma unroll
                for (int j = 0; j < 8; ++j) xv[j] = __fadd_rn(xv[j], acc[j]);
            }
        }
#pragma unroll
        for (int j = 0; j < 8; ++j)
            xbuf[lane * 36 + d0 + j] = __fadd_rn(xv[j], projb[d0 + j]);
    }
    __syncthreads();

    // residual + qsum in registers (f32, elementwise — matches ref exactly)
    float rf[ND], qs[ND];
#pragma unroll
    for (int d = 0; d < ND; ++d) { rf[d] = xbuf[lane * 36 + d]; qs[d] = 0.f; }

    float*  cnf = wlds;                  // fast cnorm filter values
    float4* mrg = (float4*)(wlds + 1024);

    // ---------- Phase C: 32 residual-VQ stages ----------
    for (int s = 0; s < NCB; ++s) {
        const float* cbs = cb + (size_t)s * NK * ND;

        __syncthreads();                 // prior-stage mrg reads done

        // fast cnorm (filter only)
#pragma unroll
        for (int u = 0; u < 4; ++u) {
            const int k = u * 256 + tid;
            const float4* c4 = (const float4*)(cbs + ((size_t)k << 5));
            float ss = 0.f;
#pragma unroll
            for (int j = 0; j < 8; ++j) {
                float4 v = c4[j];
                ss = fmaf(v.x, v.x, ss); ss = fmaf(v.y, v.y, ss);
                ss = fmaf(v.z, v.z, ss); ss = fmaf(v.w, v.w, ss);
            }
            cnf[k] = ss;
        }
        __syncthreads();

        // ---- fast FMA filter scan over this wave's 256 candidates ----
        float m1 = FLT_MAX, m2 = FLT_MAX;
        int   i1 = 0x7fffffff, i2 = 0x7fffffff;
        const int kbase = __builtin_amdgcn_readfirstlane(wv * 256);

        for (int kk = 0; kk < 256; ++kk) {
            const int k = kbase + kk;
            const float4* c4 = (const float4*)(cbs + ((size_t)k << 5));
            float a0 = 0.f, a1 = 0.f, a2 = 0.f, a3 = 0.f;
#pragma unroll
            for (int j = 0; j < 2; ++j) {
                float4 v0 = c4[j * 4 + 0];
                float4 v1 = c4[j * 4 + 1];
                float4 v2 = c4[j * 4 + 2];
                float4 v3 = c4[j * 4 + 3];
                const int o = j * 16;
                a0 = fmaf(v0.x, rf[o + 0], a0);  a0 = fmaf(v0.y, rf[o + 1], a0);
                a0 = fmaf(v0.z, rf[o + 2], a0);  a0 = fmaf(v0.w, rf[o + 3], a0);
                a1 = fmaf(v1.x, rf[o + 4], a1);  a1 = fmaf(v1.y, rf[o + 5], a1);
                a1 = fmaf(v1.z, rf[o + 6], a1);  a1 = fmaf(v1.w, rf[o + 7], a1);
                a2 = fmaf(v2.x, rf[o + 8], a2);  a2 = fmaf(v2.y, rf[o + 9], a2);
                a2 = fmaf(v2.z, rf[o + 10], a2); a2 = fmaf(v2.w, rf[o + 11], a2);
                a3 = fmaf(v3.x, rf[o + 12], a3); a3 = fmaf(v3.y, rf[o + 13], a3);
                a3 = fmaf(v3.z, rf[o + 14], a3); a3 = fmaf(v3.w, rf[o + 15], a3);
            }
            const float dot  = (a0 + a1) + (a2 + a3);
            const float dist = fmaf(-2.f, dot, cnf[k]);

            const bool l1 = dist < m1;
            const bool l2 = dist < m2;
            m2 = l1 ? m1 : (l2 ? dist : m2);
            i2 = l1 ? i1 : (l2 ? k : i2);
            m1 = l1 ? dist : m1;
            i1 = l1 ? k : i1;
        }

        mrg[wv * 64 + lane] = make_float4(m1, __int_as_float(i1), m2, __int_as_float(i2));
        __syncthreads();

        // ---- cross-wave top-2 merge (all waves redundantly, identical result) ----
        float M1 = FLT_MAX, M2 = FLT_MAX;
        int   I1 = 0x7fffffff, I2 = 0x7fffffff;
#pragma unroll
        for (int w2 = 0; w2 < 4; ++w2) {
            const float4 v = mrg[w2 * 64 + lane];
#pragma unroll
            for (int h = 0; h < 2; ++h) {
                const float m = (h == 0) ? v.x : v.z;
                const int   i = __float_as_int((h == 0) ? v.y : v.w);
                const bool b1 = (m < M1) || (m == M1 && i < I1);
                const bool b2 = (m < M2) || (m == M2 && i < I2);
                if (b1) { M2 = M1; I2 = I1; M1 = m; I1 = i; }
                else if (b2) { M2 = m; I2 = i; }
            }
        }

        // ---- exact-ref refine: decide between the two filter candidates ----
        const float d1 = exact_d_ref(rf, cbs + ((size_t)I1 << 5));
        const float d2 = exact_d_ref(rf, cbs + ((size_t)I2 << 5));
        const int kf = (d2 < d1 || (d2 == d1 && I2 < I1)) ? I2 : I1;

        // ---- update residual & qsum (elementwise f32, matches ref) ----
        {
#pragma clang fp contract(off)
            const float4* pf = (const float4*)(cbs + ((size_t)kf << 5));
#pragma unroll
            for (int j = 0; j < 8; ++j) {
                const float4 v = pf[j];
                const int o = j * 4;
                rf[o + 0] = __fsub_rn(rf[o + 0], v.x);  qs[o + 0] = __fadd_rn(qs[o + 0], v.x);
                rf[o + 1] = __fsub_rn(rf[o + 1], v.y);  qs[o + 1] = __fadd_rn(qs[o + 1], v.y);
                rf[o + 2] = __fsub_rn(rf[o + 2], v.z);  qs[o + 2] = __fadd_rn(qs[o + 2], v.z);
                rf[o + 3] = __fsub_rn(rf[o + 3], v.w);  qs[o + 3] = __fadd_rn(qs[o + 3], v.w);
            }
        }

        if (wv == 0)
            out[(size_t)NB * ND * NT + ((size_t)s * NB + b) * NT + t] = (float)kf;
    }

    // ---------- quantized output [B][D][T]: straight-through x + (qsum - x) ----------
    if (wv == 0) {
#pragma clang fp contract(off)
#pragma unroll
        for (int d = 0; d < ND; ++d) {
            const float x = xbuf[lane * 36 + d];
            const float q = __fadd_rn(x, __fsub_rn(qs[d], x));
            out[((size_t)b * ND + d) * NT + t] = q;
        }
    }
}

extern "C" void kernel_launch(void* const* d_in, const int* in_sizes, int n_in,
                              void* d_out, int out_size, void* d_ws, size_t ws_size,
                              hipStream_t stream) {
    const float* latent = (const float*)d_in[0];
    const float* projw  = (const float*)d_in[1];
    const float* projb  = (const float*)d_in[2];
    const float* cb     = (const float*)d_in[3];
    float* out = (float*)d_out;

    dim3 grid(NB * NT / 64);   // 512 blocks, 64 tokens each
    dim3 block(256);
    hipLaunchKernelGGL(rvq_kernel, grid, block, 0, stream,
                       latent, projw, projb, cb, out);
}